// Round 13
// baseline (284.911 us; speedup 1.0000x reference)
//
#include <hip/hip_runtime.h>

#define NCLS 19
#define HW   16384          // 128*128
#define CHW  4194304        // 256*16384
#define LBL_BHW 262144      // 512*512
#define MAXS 4096
#define TEMP_INV (1.0f/0.07f)
#define EPS 1e-12f
#define KC (NCLS*256)       // 4864

// ---------------- K1: per-block partial class sums (NO global atomics) -------
// grid = NB1 blocks x 256 threads; each block processes tilesPB tiles of 64
// pixels. Accumulates into LDS, flushes ONCE to a private partial buffer.
__global__ __launch_bounds__(256) void k1_partial(
    const float4* __restrict__ ft4, const int* __restrict__ tpl,
    float* __restrict__ g_part, float* __restrict__ g_cntPart, int tilesPB) {
  __shared__ float s_sums[NCLS * 257];   // stride 257 vs LDS banks
  __shared__ float s_cnt[NCLS];
  __shared__ float4 s_ssp[16][16];
  __shared__ float s_rinv[64];
  __shared__ int s_seg[64];
  int t = threadIdx.x;
  for (int i = t; i < NCLS * 257; i += 256) s_sums[i] = 0.f;
  if (t < NCLS) s_cnt[t] = 0.f;
  int q = t & 15, g = t >> 4;

  for (int it = 0; it < tilesPB; ++it) {
    int T = blockIdx.x * tilesPB + it;
    __syncthreads();                      // protect s_seg/s_ssp from prev iter
    if (t < 64) {
      int n = T * 64 + t;
      int b = n >> 14, hw = n & (HW - 1), h = hw >> 7, w = hw & 127;
      int lbl = tpl[b * LBL_BHW + h * 2048 + w * 4];   // nearest-down (4h,4w)
      int seg = (lbl >= 0 && lbl < NCLS) ? lbl : -1;
      s_seg[t] = seg;
      if (seg >= 0) atomicAdd(&s_cnt[seg], 1.f);
    }
    int n0 = T * 64;
    int b = n0 >> 14, hw0 = n0 & (HW - 1);
    size_t base4 = (size_t)b * (CHW / 4) + (size_t)(hw0 >> 2) + q;
    float4 v[16];
    float4 ssv = make_float4(0.f, 0.f, 0.f, 0.f);
    #pragma unroll
    for (int i = 0; i < 16; ++i) {
      v[i] = ft4[base4 + (size_t)(g * 16 + i) * (HW / 4)];
      ssv.x += v[i].x * v[i].x; ssv.y += v[i].y * v[i].y;
      ssv.z += v[i].z * v[i].z; ssv.w += v[i].w * v[i].w;
    }
    s_ssp[g][q] = ssv;
    __syncthreads();
    if (t < 64) {
      int qq = t >> 2, j = t & 3;
      float ss = 0.f;
      #pragma unroll
      for (int g2 = 0; g2 < 16; ++g2) ss += ((const float*)&s_ssp[g2][qq])[j];
      s_rinv[t] = 1.f / fmaxf(sqrtf(ss), EPS);
    }
    __syncthreads();
    float r0 = s_rinv[q * 4 + 0], r1 = s_rinv[q * 4 + 1];
    float r2 = s_rinv[q * 4 + 2], r3 = s_rinv[q * 4 + 3];
    int e0 = s_seg[q * 4 + 0], e1 = s_seg[q * 4 + 1];
    int e2 = s_seg[q * 4 + 2], e3 = s_seg[q * 4 + 3];
    #pragma unroll
    for (int i = 0; i < 16; ++i) {
      int c = g * 16 + i;
      if (e0 >= 0) atomicAdd(&s_sums[e0 * 257 + c], v[i].x * r0);
      if (e1 >= 0) atomicAdd(&s_sums[e1 * 257 + c], v[i].y * r1);
      if (e2 >= 0) atomicAdd(&s_sums[e2 * 257 + c], v[i].z * r2);
      if (e3 >= 0) atomicAdd(&s_sums[e3 * 257 + c], v[i].w * r3);
    }
  }
  __syncthreads();
  float* dst = g_part + (size_t)blockIdx.x * KC;   // private slice: plain stores
  for (int e = t; e < KC; e += 256) dst[e] = s_sums[(e >> 8) * 257 + (e & 255)];
  if (t < NCLS) g_cntPart[blockIdx.x * NCLS + t] = s_cnt[t];
}

// ---------------- K2: reduce partials + (last block) normalize centroids ----
// grid = 152 blocks (19 classes x 8 octants) x 256 threads (channels).
__global__ __launch_bounds__(256) void k2_reduce(
    const float* __restrict__ g_part, const float* __restrict__ g_cntPart,
    float* __restrict__ g_sums, float* __restrict__ g_cnt_raw,
    int* __restrict__ done2, float* __restrict__ g_cent,
    float* __restrict__ g_counts, int NB1) {
  int k = blockIdx.x >> 3, o = blockIdx.x & 7;
  int t = threadIdx.x;
  float sum = 0.f;
  for (int s = o; s < NB1; s += 8) sum += g_part[(size_t)s * KC + k * 256 + t];
  if (sum != 0.f) atomicAdd(&g_sums[k * 256 + t], sum);
  // counts: thread t handles partial s = o + 8t (t < NB1/8 <= 64)
  float cp = 0.f;
  int s = o + t * 8;
  if (s < NB1) cp = g_cntPart[s * NCLS + k];
  #pragma unroll
  for (int off = 32; off; off >>= 1) cp += __shfl_down(cp, off, 64);
  __shared__ float s_cred[4];
  if ((t & 63) == 0) s_cred[t >> 6] = cp;
  __syncthreads();
  __shared__ int s_last;
  if (t == 0) {
    float c4 = s_cred[0] + s_cred[1] + s_cred[2] + s_cred[3];
    if (c4 != 0.f) atomicAdd(&g_cnt_raw[k], c4);
    __threadfence();
    int old = atomicAdd(done2, 1);
    s_last = (old == 151) ? 1 : 0;
  }
  __syncthreads();
  if (!s_last) return;
  // ---- last block: normalize all 19 centroids ----
  __shared__ float s_hc[NCLS];
  __shared__ float s_red[4];
  if (t < NCLS) s_hc[t] = atomicAdd(&g_cnt_raw[t], 0.f);
  __syncthreads();
  for (int kk = 0; kk < NCLS; ++kk) {
    float ms = atomicAdd(&g_sums[kk * 256 + t], 0.f);   // coherent read
    float cnt = s_hc[kk];
    float m = ms / fmaxf(cnt, 1.f);
    float ss = m * m;
    #pragma unroll
    for (int off = 32; off; off >>= 1) ss += __shfl_down(ss, off, 64);
    if ((t & 63) == 0) s_red[t >> 6] = ss;
    __syncthreads();
    float tot = s_red[0] + s_red[1] + s_red[2] + s_red[3];
    float rinv = 1.f / fmaxf(sqrtf(tot), EPS);
    g_cent[kk * 256 + t] = m * rinv;
    if (t == 0) g_counts[kk] = cnt;
    __syncthreads();
  }
}

// ---------------- K3ab: valid counts + (last block) exclusive scan ----------
__global__ __launch_bounds__(256) void k3ab(
    const int* __restrict__ sgt, const float* __restrict__ g_counts,
    int* __restrict__ blockCounts, int* __restrict__ blockPrefix,
    int* __restrict__ totalValid, int* __restrict__ done3) {
  __shared__ float s_hc[NCLS];
  __shared__ int swv[4];
  int t = threadIdx.x;
  if (t < NCLS) s_hc[t] = g_counts[t];
  __syncthreads();
  int n = blockIdx.x * 256 + t;
  int b = n >> 14, hw = n & (HW - 1), h = hw >> 7, w = hw & 127;
  int lbl = sgt[b * LBL_BHW + h * 2048 + w * 4];
  int lc = min(max(lbl, 0), NCLS - 1);
  bool valid = (lbl != 255) && (s_hc[lc] > 0.f);
  unsigned long long m = __ballot(valid);
  if ((t & 63) == 0) swv[t >> 6] = __popcll(m);
  __syncthreads();
  __shared__ int s_last;
  if (t == 0) {
    int c = swv[0] + swv[1] + swv[2] + swv[3];
    atomicExch(&blockCounts[blockIdx.x], c);
    __threadfence();
    int old = atomicAdd(done3, 1);
    s_last = (old == 255) ? 1 : 0;
  }
  __syncthreads();
  if (!s_last) return;
  // ---- last block: scan 256 counts ----
  __shared__ int s[256];
  int own = atomicAdd(&blockCounts[t], 0);
  s[t] = own;
  __syncthreads();
  for (int off = 1; off < 256; off <<= 1) {
    int v = (t >= off) ? s[t - off] : 0;
    __syncthreads();
    s[t] += v;
    __syncthreads();
  }
  blockPrefix[t] = s[t] - own;
  if (t == 255) *totalValid = s[255];
}

// ---------------- K3c: compact indices of first MAXS valid pixels -----------
__global__ __launch_bounds__(256) void k3c_compact(
    const int* __restrict__ sgt, const float* __restrict__ g_counts,
    const int* __restrict__ blockPrefix, int* __restrict__ sel) {
  __shared__ float s_hc[NCLS];
  __shared__ int swv[4];
  int t = threadIdx.x;
  if (t < NCLS) s_hc[t] = g_counts[t];
  __syncthreads();
  int n = blockIdx.x * 256 + t;
  int b = n >> 14, hw = n & (HW - 1), h = hw >> 7, w = hw & 127;
  int lbl = sgt[b * LBL_BHW + h * 2048 + w * 4];
  int lc = min(max(lbl, 0), NCLS - 1);
  bool valid = (lbl != 255) && (s_hc[lc] > 0.f);
  unsigned long long m = __ballot(valid);
  int lane = t & 63, wv = t >> 6;
  int lanePre = __popcll(m & ((1ull << lane) - 1ull));
  if (lane == 0) swv[wv] = __popcll(m);
  __syncthreads();
  int wavePre = 0;
  for (int i = 0; i < wv; ++i) wavePre += swv[i];
  int rank = blockPrefix[blockIdx.x] + wavePre + lanePre;
  if (valid && rank < MAXS) sel[rank] = n;
}

// ---------------- K3d: CE over selected pixels + finalize -------------------
__global__ __launch_bounds__(256) void k3d_ce(
    const float* __restrict__ fa, const int* __restrict__ sgt,
    const float* __restrict__ g_counts, const float* __restrict__ g_cent,
    const int* __restrict__ sel, const int* __restrict__ totalValid,
    float* __restrict__ loss_sum, int* __restrict__ done,
    float* __restrict__ out) {
  __shared__ float s_cent[NCLS * 256];
  __shared__ float s_hc[NCLS];
  __shared__ float s_red[16 * 21];
  __shared__ int s_n[16];
  __shared__ int s_lb[16];
  int t = threadIdx.x;
  for (int i = t; i < NCLS * 64; i += 256)
    ((float4*)s_cent)[i] = ((const float4*)g_cent)[i];
  if (t < NCLS) s_hc[t] = g_counts[t];
  for (int i = t; i < 16 * 21; i += 256) s_red[i] = 0.f;
  int nsel = min(*totalValid, MAXS);
  if (t < 16) {
    int mi = blockIdx.x * 16 + t;
    int n = (mi < nsel) ? sel[mi] : 0;
    s_n[t] = n;
    int b = n >> 14, hw = n & (HW - 1), h = hw >> 7, w = hw & 127;
    int lbl = sgt[b * LBL_BHW + h * 2048 + w * 4];
    s_lb[t] = min(max(lbl, 0), NCLS - 1);
  }
  __syncthreads();

  int p = t & 15, g = t >> 4;
  int n = s_n[p];
  int b = n >> 14, hw = n & (HW - 1);
  size_t base = (size_t)b * CHW + hw;
  float dot[NCLS];
  #pragma unroll
  for (int k = 0; k < NCLS; ++k) dot[k] = 0.f;
  float ss = 0.f;
  #pragma unroll
  for (int i = 0; i < 16; ++i) {
    int c = g * 16 + i;
    float v = fa[base + (size_t)c * HW];
    ss += v * v;
    #pragma unroll
    for (int k = 0; k < NCLS; ++k) dot[k] += v * s_cent[k * 256 + c];
  }
  #pragma unroll
  for (int k = 0; k < NCLS; ++k) atomicAdd(&s_red[p * 21 + k], dot[k]);
  atomicAdd(&s_red[p * 21 + 19], ss);
  __syncthreads();

  float ce = 0.f;
  if (t < 16) {
    int mi = blockIdx.x * 16 + t;
    if (mi < nsel) {
      float rinv = 1.f / fmaxf(sqrtf(s_red[t * 21 + 19]), EPS);
      float mx = -3.402823466e38f;
      float sim[NCLS];
      #pragma unroll
      for (int k = 0; k < NCLS; ++k) {
        float sk = (s_hc[k] > 0.f) ? s_red[t * 21 + k] * rinv * TEMP_INV : -1e9f;
        sim[k] = sk;
        mx = fmaxf(mx, sk);
      }
      float sum = 0.f;
      #pragma unroll
      for (int k = 0; k < NCLS; ++k) sum += expf(sim[k] - mx);
      ce = mx + logf(sum) - sim[s_lb[t]];
    }
  }
  #pragma unroll
  for (int off = 32; off; off >>= 1) ce += __shfl_down(ce, off, 64);
  if (t == 0) {
    atomicAdd(loss_sum, ce);
    __threadfence();
    int old = atomicAdd(done, 1);
    if (old == (int)gridDim.x - 1) {
      float tl = atomicAdd(loss_sum, 0.f);
      out[0] = tl / fmaxf((float)nsel, 1.f);
    }
  }
}

// ---------------- workspace layout ----------------
// zeroed region:
#define WS_SUMS     0          // float[4864] = 19456
#define WS_CNTRAW   19456      // float[19]
#define WS_DONE2    19536
#define WS_DONE3    19540
#define WS_DONE4    19544
#define WS_LOSS     19548
#define WS_TOTAL    19552
#define WS_ZERO_END 19584
// non-zeroed:
#define WS_COUNTS   19584      // float[19]
#define WS_CENT     19712      // float[4864] -> 39168
#define WS_BCNT     39168      // int[256]
#define WS_BPRE     40192      // int[256]
#define WS_SEL      41216      // int[4096] -> 57600
#define WS_PART     57600      // float[NB1*4864], then float[NB1*19]

extern "C" void kernel_launch(void* const* d_in, const int* in_sizes, int n_in,
                              void* d_out, int out_size, void* d_ws, size_t ws_size,
                              hipStream_t stream) {
  const float* f_aug = (const float*)d_in[0];
  const float* f_t = (const float*)d_in[1];
  const int* source_gt = (const int*)d_in[2];
  const int* target_pseudo = (const int*)d_in[3];
  float* out = (float*)d_out;

  // pick largest partial-buffer count that fits ws (deterministic per session)
  int NB1 = 4;
  for (int cand = 512; cand >= 4; cand >>= 1) {
    size_t need = (size_t)WS_PART + (size_t)cand * (KC * 4 + NCLS * 4);
    if (need <= ws_size) { NB1 = cand; break; }
  }
  int tilesPB = 1024 / NB1;

  char* ws = (char*)d_ws;
  float* g_sums = (float*)(ws + WS_SUMS);
  float* g_cnt_raw = (float*)(ws + WS_CNTRAW);
  int* done2 = (int*)(ws + WS_DONE2);
  int* done3 = (int*)(ws + WS_DONE3);
  int* done4 = (int*)(ws + WS_DONE4);
  float* loss_sum = (float*)(ws + WS_LOSS);
  int* totalValid = (int*)(ws + WS_TOTAL);
  float* g_counts = (float*)(ws + WS_COUNTS);
  float* g_cent = (float*)(ws + WS_CENT);
  int* blockCounts = (int*)(ws + WS_BCNT);
  int* blockPrefix = (int*)(ws + WS_BPRE);
  int* sel = (int*)(ws + WS_SEL);
  float* g_part = (float*)(ws + WS_PART);
  float* g_cntPart = (float*)(ws + WS_PART + (size_t)NB1 * KC * 4);

  hipMemsetAsync(d_ws, 0, WS_ZERO_END, stream);

  k1_partial<<<NB1, 256, 0, stream>>>((const float4*)f_t, target_pseudo,
                                      g_part, g_cntPart, tilesPB);
  k2_reduce<<<NCLS * 8, 256, 0, stream>>>(g_part, g_cntPart, g_sums, g_cnt_raw,
                                          done2, g_cent, g_counts, NB1);
  k3ab<<<256, 256, 0, stream>>>(source_gt, g_counts, blockCounts, blockPrefix,
                                totalValid, done3);
  k3c_compact<<<256, 256, 0, stream>>>(source_gt, g_counts, blockPrefix, sel);
  k3d_ce<<<256, 256, 0, stream>>>(f_aug, source_gt, g_counts, g_cent, sel,
                                  totalValid, loss_sum, done4, out);
}